// Round 9
// baseline (235.162 us; speedup 1.0000x reference)
//
#include <hip/hip_runtime.h>

#define BATCH    1024
#define NUM_VARS 2048
#define LEAVES   (2 * NUM_VARS)              // 4096
#define LEVELS   12
#define WIDTH    4096
#define TOTAL    (LEAVES + LEVELS * WIDTH)   // 53248

#define BSLICE     64                        // batch elems per eval block
#define NEVB       (BATCH / BSLICE)          // 16 eval blocks
#define MAXS       224                       // LDS-resident slots (57 KB)
#define MAX_SLOTS  (LEVELS * WIDTH)          // worst-case active nodes
#define SPILL_SLOTS (MAX_SLOTS - MAXS)

// ---------------------------------------------------------------------------
// Transpose x[1024][2048] -> xT[2048][1024] so leaf reads in eval are
// coalesced 256 B rows. Leaves stay implicit (1-x computed on the fly).
// ---------------------------------------------------------------------------
__global__ __launch_bounds__(1024) void transpose_kernel(const float* __restrict__ x,
                                                         float* __restrict__ xT)
{
    __shared__ float tile[64][65];
    const int v0 = blockIdx.x * 64;
    const int bb = blockIdx.y * 64;
    const int tv = threadIdx.x;               // 0..63
    const int tb = threadIdx.y;               // 0..15
    #pragma unroll
    for (int i = 0; i < 4; ++i) {
        const int bl = tb + i * 16;
        tile[tv][bl] = x[(size_t)(bb + bl) * NUM_VARS + v0 + tv];   // coalesced in tv
    }
    __syncthreads();
    const int wb = threadIdx.x;
    #pragma unroll
    for (int i = 0; i < 4; ++i) {
        const int vl = tb + i * 16;
        xT[(size_t)(v0 + vl) * BATCH + bb + wb] = tile[vl][wb];      // coalesced in wb
    }
}

// ---------------------------------------------------------------------------
// Single-block backward reachability + compact record build.
// Flags live in LDS (53 KB). Backward pass marks children of marked nodes
// (all marks target strictly lower ids -> __syncthreads suffices). Forward
// pass assigns compact slots per level (order within a level is arbitrary)
// and bakes records: enc4[slot] = encoded children (leaf c -> c-8192 < 0,
// internal c -> slot_of[c]), ops[slot] = op, counts[l] = actives at level l.
// ---------------------------------------------------------------------------
__global__ __launch_bounds__(1024) void mark_build_kernel(const int4* __restrict__ child4,
                                                          const int*  __restrict__ op_type,
                                                          int4* __restrict__ enc4,
                                                          int*  __restrict__ ops,
                                                          int*  __restrict__ counts,
                                                          int*  __restrict__ slot_of)
{
    __shared__ unsigned char flg[TOTAL];
    __shared__ int cnt;
    __shared__ int slotbase;
    const int tid = threadIdx.x;

    for (int i = tid; i < TOTAL / 4; i += 1024) ((unsigned int*)flg)[i] = 0u;
    __syncthreads();
    if (tid == 0) flg[TOTAL - 1] = 1;         // root
    __syncthreads();

    for (int l = LEVELS - 1; l >= 0; --l) {   // backward marking
        const int base = LEAVES + l * WIDTH;
        for (int k = tid; k < WIDTH; k += 1024) {
            if (flg[base + k]) {
                const int4 c = child4[l * WIDTH + k];
                flg[c.x] = 1; flg[c.y] = 1; flg[c.z] = 1; flg[c.w] = 1;
            }
        }
        __syncthreads();
    }

    if (tid == 0) slotbase = 0;
    __syncthreads();

    for (int l = 0; l < LEVELS; ++l) {        // forward slot assignment
        if (tid == 0) cnt = 0;
        __syncthreads();
        const int base = LEAVES + l * WIDTH;
        for (int k = tid; k < WIDTH; k += 1024) {
            if (flg[base + k]) {
                const int pos  = atomicAdd(&cnt, 1);
                const int slot = slotbase + pos;
                slot_of[base + k] = slot;     // children lookups are lower levels,
                const int4 c = child4[l * WIDTH + k];   // already assigned+synced
                int4 e;
                e.x = (c.x < LEAVES) ? (c.x - 2 * LEAVES) : slot_of[c.x];
                e.y = (c.y < LEAVES) ? (c.y - 2 * LEAVES) : slot_of[c.y];
                e.z = (c.z < LEAVES) ? (c.z - 2 * LEAVES) : slot_of[c.z];
                e.w = (c.w < LEAVES) ? (c.w - 2 * LEAVES) : slot_of[c.w];
                enc4[slot] = e;
                ops[slot]  = op_type[l * WIDTH + k];
            }
        }
        __syncthreads();
        if (tid == 0) { counts[l] = cnt; slotbase += cnt; }
        __syncthreads();
    }
}

// ---------------------------------------------------------------------------
// Fused evaluation: block b owns batch slice [b*64, b*64+64). All levels in
// one kernel; per-level __syncthreads (block-local dependencies only).
// Node values in LDS val[MAXS][64] (2-way bank aliasing = free); slots
// beyond MAXS spill to a per-block global region (correct for any instance).
// ---------------------------------------------------------------------------
__global__ __launch_bounds__(256) void eval_kernel(const float* __restrict__ xT,
                                                   const int4* __restrict__ enc4,
                                                   const int*  __restrict__ ops,
                                                   const int*  __restrict__ counts,
                                                   float* __restrict__ spill_all,
                                                   float* __restrict__ out)
{
    __shared__ float val[MAXS][BSLICE];
    const int lane = threadIdx.x & 63;
    const int wave = threadIdx.x >> 6;        // 4 waves: node-parallel in level
    const int b0   = blockIdx.x * BSLICE;
    float* spill = spill_all + (size_t)blockIdx.x * SPILL_SLOTS * BSLICE;

    int slotbase = 0;
    for (int l = 0; l < LEVELS; ++l) {
        const int n = counts[l];
        for (int i = wave; i < n; i += 4) {
            const int  slot = slotbase + i;
            const int4 e = enc4[slot];        // wave-uniform
            const int  o = ops[slot];
            const int  es[4] = {e.x, e.y, e.z, e.w};
            float v[4];
            #pragma unroll
            for (int j = 0; j < 4; ++j) {
                const int s = es[j];          // wave-uniform branches
                float t;
                if (s < 0) {                  // leaf: decode id
                    const int c = s + 2 * LEAVES;       // [0, 4096)
                    if (c < NUM_VARS)
                        t = xT[(size_t)c * BATCH + b0 + lane];
                    else
                        t = 1.0f - xT[(size_t)(c - NUM_VARS) * BATCH + b0 + lane];
                } else if (s < MAXS) {
                    t = val[s][lane];
                } else {
                    t = spill[(size_t)(s - MAXS) * BSLICE + lane];
                }
                v[j] = t;
            }
            const float r = (o == 0) ? ((v[0] * v[1]) * v[2]) * v[3]   // np.prod order
                                     : ((v[0] + v[1]) + v[2]) + v[3];  // np.sum order
            if (slot < MAXS) val[slot][lane] = r;
            else             spill[(size_t)(slot - MAXS) * BSLICE + lane] = r;
            if (l == LEVELS - 1) out[b0 + lane] = r;   // root (sole level-11 entry)
        }
        __syncthreads();
        slotbase += n;
    }
}

extern "C" void kernel_launch(void* const* d_in, const int* in_sizes, int n_in,
                              void* d_out, int out_size, void* d_ws, size_t ws_size,
                              hipStream_t stream)
{
    const float* x       = (const float*)d_in[0];
    const int4*  child4  = (const int4*)d_in[1];
    const int*   op_type = (const int*)d_in[2];
    float*       out     = (float*)d_out;

    // ws layout (total ~210 MB < 256 MiB):
    char* w = (char*)d_ws;
    float* xT      = (float*)w;  w += (size_t)NUM_VARS * BATCH * sizeof(float); // 8 MB
    int4*  enc4    = (int4*)w;   w += (size_t)MAX_SLOTS * sizeof(int4);         // 786 KB
    int*   ops     = (int*)w;    w += (size_t)MAX_SLOTS * sizeof(int);          // 196 KB
    int*   counts  = (int*)w;    w += 64;
    int*   slot_of = (int*)w;    w += (size_t)TOTAL * sizeof(int);              // 208 KB
    float* spill   = (float*)w;  // NEVB * SPILL_SLOTS * BSLICE * 4 ≈ 200 MB

    {
        dim3 blk(64, 16);
        dim3 grd(NUM_VARS / 64, BATCH / 64);
        transpose_kernel<<<grd, blk, 0, stream>>>(x, xT);
    }
    mark_build_kernel<<<1, 1024, 0, stream>>>(child4, op_type, enc4, ops,
                                              counts, slot_of);
    eval_kernel<<<NEVB, 256, 0, stream>>>(xT, enc4, ops, counts, spill, out);
}

// Round 10
// 168.574 us; speedup vs baseline: 1.3950x; 1.3950x over previous
//
#include <hip/hip_runtime.h>

#define BATCH    1024
#define NUM_VARS 2048
#define LEAVES   (2 * NUM_VARS)              // 4096
#define LEVELS   12
#define WIDTH    4096
#define TOTAL    (LEAVES + LEVELS * WIDTH)   // 53248
#define NWORDS   (TOTAL / 32)                // 1664 bitmask words

#define CAP      2048                        // max active internal nodes (expect ~150)
#define ENC_CAP  768                         // enc records cached in eval LDS
#define MAXS     192                         // LDS value slots in eval
#define BSLICE   64                          // batch elems per eval block
#define NEVB     (BATCH / BSLICE)            // 16 eval blocks
#define ETHR     512                         // 8 waves per eval block

// ---------------------------------------------------------------------------
// Transpose x[1024][2048] -> xT[2048][1024] so leaf reads in eval are
// coalesced 256 B rows. Leaves stay implicit (1-x applied at combine).
// ---------------------------------------------------------------------------
__global__ __launch_bounds__(1024) void transpose_kernel(const float* __restrict__ x,
                                                         float* __restrict__ xT)
{
    __shared__ float tile[64][65];
    const int v0 = blockIdx.x * 64;
    const int bb = blockIdx.y * 64;
    const int tv = threadIdx.x;               // 0..63
    const int tb = threadIdx.y;               // 0..15
    #pragma unroll
    for (int i = 0; i < 4; ++i) {
        const int bl = tb + i * 16;
        tile[tv][bl] = x[(size_t)(bb + bl) * NUM_VARS + v0 + tv];   // coalesced in tv
    }
    __syncthreads();
    const int wb = threadIdx.x;
    #pragma unroll
    for (int i = 0; i < 4; ++i) {
        const int vl = tb + i * 16;
        xT[(size_t)(v0 + vl) * BATCH + bb + wb] = tile[vl][wb];      // coalesced in wb
    }
}

// lower_bound over sorted LDS list; child guaranteed present.
__device__ __forceinline__ int enc_child(int c, const int* __restrict__ nid, int hi)
{
    if (c < LEAVES) return c - 2 * LEAVES;    // leaf code in [-8192,-4096)
    int lo = 0;
    while (lo < hi) {
        const int mid = (lo + hi) >> 1;
        if (nid[mid] < c) lo = mid + 1; else hi = mid;
    }
    return lo;                                // slot id
}

// ---------------------------------------------------------------------------
// Reachability + compact record build, single block, all LDS.
// Backward: bitmask marking with one batched parallel child4 load per level.
// Forward: order-preserving compaction (wave 0: popc + shfl scan) into the
// globally sorted nid[] list; one parallel child4/op load round per level;
// child slots resolved by LDS binary search (no global slot_of).
// ---------------------------------------------------------------------------
__global__ __launch_bounds__(1024) void mark_build_kernel(const int4* __restrict__ child4,
                                                          const int*  __restrict__ op_type,
                                                          int4* __restrict__ enc4,
                                                          int*  __restrict__ ops,
                                                          int*  __restrict__ counts)
{
    __shared__ unsigned int flg[NWORDS];      // 6.5 KB bitmask over node ids
    __shared__ int nid[CAP];                  // sorted active internal node ids
    __shared__ int frontier[CAP];
    __shared__ int fcnt, lvl_cnt, sbase;
    const int tid = threadIdx.x;

    for (int i = tid; i < NWORDS; i += 1024) flg[i] = 0u;
    __syncthreads();
    if (tid == 0) { flg[NWORDS - 1] = 0x80000000u; sbase = 0; }  // root = TOTAL-1
    __syncthreads();

    // ---- backward marking ----
    for (int l = LEVELS - 1; l >= 0; --l) {
        if (tid == 0) fcnt = 0;
        __syncthreads();
        if (tid < 128) {                      // level-l occupies 128 words
            unsigned int w = flg[128 * (l + 1) + tid];
            while (w) {
                const int b = __ffs(w) - 1; w &= w - 1;
                const int pos = atomicAdd(&fcnt, 1);
                if (pos < CAP) frontier[pos] = LEAVES + l * WIDTH + 32 * tid + b;
            }
        }
        __syncthreads();
        int fc = fcnt; if (fc > CAP) fc = CAP;
        for (int i = tid; i < fc; i += 1024) {            // parallel child4 loads
            const int4 c = child4[frontier[i] - LEAVES];
            atomicOr(&flg[c.x >> 5], 1u << (c.x & 31));
            atomicOr(&flg[c.y >> 5], 1u << (c.y & 31));
            atomicOr(&flg[c.z >> 5], 1u << (c.z & 31));
            atomicOr(&flg[c.w >> 5], 1u << (c.w & 31));
        }
        __syncthreads();
    }

    // ---- forward: sorted compaction + record build ----
    for (int l = 0; l < LEVELS; ++l) {
        if (tid < 64) {                       // wave 0: order-preserving compaction
            const int lane = tid;
            const unsigned int w0 = flg[128 * (l + 1) + 2 * lane];
            const unsigned int w1 = flg[128 * (l + 1) + 2 * lane + 1];
            const int pc = __popc(w0) + __popc(w1);
            int scan = pc;
            for (int d = 1; d < 64; d <<= 1) {
                const int up = __shfl_up(scan, d, 64);
                if (lane >= d) scan += up;
            }
            int base = sbase + scan - pc;
            const int nd0 = LEAVES + l * WIDTH + 64 * lane;
            unsigned int w = w0;
            while (w) { const int b = __ffs(w) - 1; w &= w - 1;
                        if (base < CAP) nid[base] = nd0 + b;       base++; }
            w = w1;
            while (w) { const int b = __ffs(w) - 1; w &= w - 1;
                        if (base < CAP) nid[base] = nd0 + 32 + b;  base++; }
            if (lane == 63) lvl_cnt = scan;
        }
        __syncthreads();
        const int n  = lvl_cnt;
        const int sb = sbase;
        for (int i = tid; i < n; i += 1024) {             // parallel record build
            const int slot = sb + i;
            if (slot >= CAP) break;
            const int nd = nid[slot];
            const int4 c = child4[nd - LEAVES];
            const int  o = op_type[nd - LEAVES];
            int4 e;
            e.x = enc_child(c.x, nid, sb);
            e.y = enc_child(c.y, nid, sb);
            e.z = enc_child(c.z, nid, sb);
            e.w = enc_child(c.w, nid, sb);
            enc4[slot] = e;
            ops[slot]  = o;
        }
        __syncthreads();
        if (tid == 0) { counts[l] = n; sbase = sb + n; }
        __syncthreads();
    }
}

// ---------------------------------------------------------------------------
// Fused evaluation. Block b owns batch slice [b*64, b*64+64); 8 waves share
// the nodes of each level in chunks of 4 -> up to 16 independent child
// fetches in flight per wave before any use (latency batched). Records are
// LDS-preloaded; values live in val[MAXS][64] (2-way bank alias = free);
// global spill covers slot overflow (never expected).
// ---------------------------------------------------------------------------
__global__ __launch_bounds__(ETHR) void eval_kernel(const float* __restrict__ xT,
                                                    const int4* __restrict__ enc4g,
                                                    const int*  __restrict__ opsg,
                                                    const int*  __restrict__ countsg,
                                                    float* __restrict__ spill_all,
                                                    float* __restrict__ out)
{
    __shared__ float val[MAXS][BSLICE];       // 48 KB
    __shared__ int4  enc_s[ENC_CAP];          // 12 KB
    __shared__ unsigned char ops_s[ENC_CAP];
    __shared__ int counts_s[LEVELS];
    const int tid  = threadIdx.x;
    const int lane = tid & 63;
    const int wave = tid >> 6;                // 0..7
    const int b0   = blockIdx.x * BSLICE;
    float* spill = spill_all + (size_t)blockIdx.x * (CAP - MAXS) * BSLICE;

    for (int i = tid; i < ENC_CAP; i += ETHR) {           // coalesced preload
        enc_s[i] = enc4g[i];
        ops_s[i] = (unsigned char)opsg[i];
    }
    if (tid < LEVELS) counts_s[tid] = countsg[tid];
    __syncthreads();

    int sb = 0;
    for (int l = 0; l < LEVELS; ++l) {
        const int n = counts_s[l];
        for (int i0 = wave * 4; i0 < n; i0 += 32) {
            float v[4][4];
            int   omask[4];                   // op + complement flags per node
            int   cmask[4];
            // ---- gather phase: all loads issued before any use ----
            #pragma unroll
            for (int j = 0; j < 4; ++j) {
                const int i = i0 + j;
                if (i >= n) break;
                const int slot = sb + i;
                const int4 e = (slot < ENC_CAP) ? enc_s[slot] : enc4g[slot];
                omask[j] = (slot < ENC_CAP) ? ops_s[slot] : opsg[slot];
                const int es[4] = {e.x, e.y, e.z, e.w};
                int cm = 0;
                #pragma unroll
                for (int k = 0; k < 4; ++k) {
                    const int s = es[k];      // wave-uniform
                    float t;
                    if (s < 0) {              // leaf
                        const int cc = s + 2 * LEAVES;          // [0, 4096)
                        t = xT[(size_t)(cc & (NUM_VARS - 1)) * BATCH + b0 + lane];
                        if (cc >= NUM_VARS) cm |= (1 << k);     // complement later
                    } else if (s < MAXS) {
                        t = val[s][lane];
                    } else {
                        t = spill[(size_t)(s - MAXS) * BSLICE + lane];
                    }
                    v[j][k] = t;
                }
                cmask[j] = cm;
            }
            // ---- combine phase ----
            #pragma unroll
            for (int j = 0; j < 4; ++j) {
                const int i = i0 + j;
                if (i >= n) break;
                const int slot = sb + i;
                float c0 = (cmask[j] & 1) ? 1.0f - v[j][0] : v[j][0];
                float c1 = (cmask[j] & 2) ? 1.0f - v[j][1] : v[j][1];
                float c2 = (cmask[j] & 4) ? 1.0f - v[j][2] : v[j][2];
                float c3 = (cmask[j] & 8) ? 1.0f - v[j][3] : v[j][3];
                const float r = (omask[j] == 0)
                    ? ((c0 * c1) * c2) * c3                     // np.prod order
                    : ((c0 + c1) + c2) + c3;                    // np.sum order
                if (slot < MAXS) val[slot][lane] = r;
                else spill[(size_t)(slot - MAXS) * BSLICE + lane] = r;
                if (l == LEVELS - 1 && i == n - 1) out[b0 + lane] = r;  // root
            }
        }
        __syncthreads();
        sb += n;
    }
}

extern "C" void kernel_launch(void* const* d_in, const int* in_sizes, int n_in,
                              void* d_out, int out_size, void* d_ws, size_t ws_size,
                              hipStream_t stream)
{
    const float* x       = (const float*)d_in[0];
    const int4*  child4  = (const int4*)d_in[1];
    const int*   op_type = (const int*)d_in[2];
    float*       out     = (float*)d_out;

    char* w = (char*)d_ws;
    float* xT     = (float*)w;  w += (size_t)NUM_VARS * BATCH * sizeof(float); // 8 MB
    int4*  enc4   = (int4*)w;   w += (size_t)CAP * sizeof(int4);               // 32 KB
    int*   ops    = (int*)w;    w += (size_t)CAP * sizeof(int);                // 8 KB
    int*   counts = (int*)w;    w += 64;
    float* spill  = (float*)w;  // NEVB * (CAP-MAXS) * BSLICE * 4 ≈ 7.6 MB

    {
        dim3 blk(64, 16);
        dim3 grd(NUM_VARS / 64, BATCH / 64);
        transpose_kernel<<<grd, blk, 0, stream>>>(x, xT);
    }
    mark_build_kernel<<<1, 1024, 0, stream>>>(child4, op_type, enc4, ops, counts);
    eval_kernel<<<NEVB, ETHR, 0, stream>>>(xT, enc4, ops, counts, spill, out);
}

// Round 11
// 165.216 us; speedup vs baseline: 1.4234x; 1.0203x over previous
//
#include <hip/hip_runtime.h>

#define BATCH    1024
#define NUM_VARS 2048
#define LEAVES   (2 * NUM_VARS)              // 4096
#define LEVELS   12
#define WIDTH    4096
#define TOTAL    (LEAVES + LEVELS * WIDTH)   // 53248
#define NWORDS   (TOTAL / 32)                // 1664 bitmask words

#define CAP      2048                        // max tracked active nodes (expect ~150)
#define ENC_CAP  256                         // enc records cached in eval LDS
#define MAXS     192                         // LDS value slots in eval
#define BSLICE   64                          // batch elems per eval block
#define NEVB     (BATCH / BSLICE)            // 16 eval blocks
#define ETHR     512                         // 8 waves per eval block
#define CHUNK    8                           // nodes per wave per gather round

// ---------------------------------------------------------------------------
// Transpose x[1024][2048] -> xT[2048][1024] so eval leaf reads are coalesced
// 256 B rows. Leaves stay implicit (1-x applied at combine).
// ---------------------------------------------------------------------------
__global__ __launch_bounds__(1024) void transpose_kernel(const float* __restrict__ x,
                                                         float* __restrict__ xT)
{
    __shared__ float tile[64][65];
    const int v0 = blockIdx.x * 64;
    const int bb = blockIdx.y * 64;
    const int tv = threadIdx.x;
    const int tb = threadIdx.y;
    #pragma unroll
    for (int i = 0; i < 4; ++i) {
        const int bl = tb + i * 16;
        tile[tv][bl] = x[(size_t)(bb + bl) * NUM_VARS + v0 + tv];
    }
    __syncthreads();
    const int wb = threadIdx.x;
    #pragma unroll
    for (int i = 0; i < 4; ++i) {
        const int vl = tb + i * 16;
        xT[(size_t)(v0 + vl) * BATCH + bb + wb] = tile[vl][wb];
    }
}

// ---------------------------------------------------------------------------
// Reachability + record build, single block.
// Backward: 12 sequential frontier-marking phases (inherent).
// Forward: ALL levels compacted in parallel (wave w <-> level w), then ONE
// parallel record-build pass; child slot lookup = 4-way interleaved
// branchless binary search over the globally sorted nid[] (11 fixed rounds).
// ---------------------------------------------------------------------------
__global__ __launch_bounds__(1024) void mark_build_kernel(const int4* __restrict__ child4,
                                                          const int*  __restrict__ op_type,
                                                          int4* __restrict__ enc4,
                                                          int*  __restrict__ ops,
                                                          int*  __restrict__ counts)
{
    __shared__ unsigned int flg[NWORDS];      // 6.5 KB bitmask
    __shared__ int nid[CAP];                  // sorted active node ids
    __shared__ int frontier[CAP];
    __shared__ int lvl_cnt[LEVELS], lvl_base[LEVELS];
    __shared__ int fcnt, total_s;
    const int tid  = threadIdx.x;
    const int lane = tid & 63;
    const int wv   = tid >> 6;                // 0..15

    for (int i = tid; i < NWORDS; i += 1024) flg[i] = 0u;
    __syncthreads();
    if (tid == 0) flg[NWORDS - 1] = 0x80000000u;          // root = TOTAL-1
    __syncthreads();

    // ---- backward marking (12 serial phases) ----
    for (int l = LEVELS - 1; l >= 0; --l) {
        if (tid == 0) fcnt = 0;
        __syncthreads();
        if (tid < 128) {                      // level-l = 128 words
            unsigned int w = flg[128 * (l + 1) + tid];
            while (w) {
                const int b = __ffs(w) - 1; w &= w - 1;
                const int pos = atomicAdd(&fcnt, 1);
                if (pos < CAP) frontier[pos] = l * WIDTH + 32 * tid + b;
            }
        }
        __syncthreads();
        int fc = fcnt; if (fc > CAP) fc = CAP;
        for (int i = tid; i < fc; i += 1024) {            // parallel child4 loads
            const int4 c = child4[frontier[i]];
            atomicOr(&flg[c.x >> 5], 1u << (c.x & 31));
            atomicOr(&flg[c.y >> 5], 1u << (c.y & 31));
            atomicOr(&flg[c.z >> 5], 1u << (c.z & 31));
            atomicOr(&flg[c.w >> 5], 1u << (c.w & 31));
        }
        __syncthreads();
    }

    // ---- forward A: all 12 levels compacted in parallel ----
    if (wv < LEVELS) {                        // wave wv owns level wv
        const unsigned int w0 = flg[128 * (wv + 1) + 2 * lane];
        const unsigned int w1 = flg[128 * (wv + 1) + 2 * lane + 1];
        const int pc = __popc(w0) + __popc(w1);
        int scan = pc;
        for (int d = 1; d < 64; d <<= 1) {
            const int up = __shfl_up(scan, d, 64);
            if (lane >= d) scan += up;
        }
        if (lane == 63) lvl_cnt[wv] = scan;
    }
    __syncthreads();
    if (tid == 0) {                           // exclusive scan of 12 counts
        int s = 0;
        for (int l = 0; l < LEVELS; ++l) { lvl_base[l] = s; s += lvl_cnt[l]; }
        total_s = s;
        for (int l = 0; l < LEVELS; ++l) counts[l] = lvl_cnt[l];
    }
    __syncthreads();
    if (wv < LEVELS) {                        // write sorted ids
        const unsigned int w0 = flg[128 * (wv + 1) + 2 * lane];
        const unsigned int w1 = flg[128 * (wv + 1) + 2 * lane + 1];
        const int pc = __popc(w0) + __popc(w1);
        int scan = pc;
        for (int d = 1; d < 64; d <<= 1) {
            const int up = __shfl_up(scan, d, 64);
            if (lane >= d) scan += up;
        }
        int base = lvl_base[wv] + scan - pc;
        const int nd0 = LEAVES + wv * WIDTH + 64 * lane;
        unsigned int w = w0;
        while (w) { const int b = __ffs(w) - 1; w &= w - 1;
                    if (base < CAP) nid[base] = nd0 + b;      base++; }
        w = w1;
        while (w) { const int b = __ffs(w) - 1; w &= w - 1;
                    if (base < CAP) nid[base] = nd0 + 32 + b; base++; }
    }
    __syncthreads();

    // ---- forward B: one parallel record-build pass ----
    const int S = (total_s < CAP) ? total_s : CAP;
    for (int slot = tid; slot < S; slot += 1024) {
        const int nd = nid[slot];
        const int4 c = child4[nd - LEAVES];   // parallel global loads
        const int  o = op_type[nd - LEAVES];
        // 4-way interleaved branchless binary search over nid[0..S)
        int lo0 = 0, lo1 = 0, lo2 = 0, lo3 = 0;
        int hi0 = S, hi1 = S, hi2 = S, hi3 = S;
        #pragma unroll
        for (int it = 0; it < 11; ++it) {     // 2^11 >= CAP
            const int m0 = (lo0 + hi0) >> 1, m1 = (lo1 + hi1) >> 1;
            const int m2 = (lo2 + hi2) >> 1, m3 = (lo3 + hi3) >> 1;
            const int n0 = nid[m0], n1 = nid[m1], n2 = nid[m2], n3 = nid[m3];
            if (lo0 < hi0) { if (n0 < c.x) lo0 = m0 + 1; else hi0 = m0; }
            if (lo1 < hi1) { if (n1 < c.y) lo1 = m1 + 1; else hi1 = m1; }
            if (lo2 < hi2) { if (n2 < c.z) lo2 = m2 + 1; else hi2 = m2; }
            if (lo3 < hi3) { if (n3 < c.w) lo3 = m3 + 1; else hi3 = m3; }
        }
        int4 e;
        e.x = (c.x < LEAVES) ? (c.x - 2 * LEAVES) : lo0;
        e.y = (c.y < LEAVES) ? (c.y - 2 * LEAVES) : lo1;
        e.z = (c.z < LEAVES) ? (c.z - 2 * LEAVES) : lo2;
        e.w = (c.w < LEAVES) ? (c.w - 2 * LEAVES) : lo3;
        enc4[slot] = e;
        ops[slot]  = o;
    }
}

// ---------------------------------------------------------------------------
// Fused evaluation. Block b owns batch slice [b*64, b*64+64); 8 waves; each
// wave gathers CHUNK=8 nodes x 4 children = 32 loads per round with NO
// control-flow breaks (dummy slot pads the tail; only stores are guarded).
// ---------------------------------------------------------------------------
__global__ __launch_bounds__(ETHR, 2) void eval_kernel(const float* __restrict__ xT,
                                                       const int4* __restrict__ enc4g,
                                                       const int*  __restrict__ opsg,
                                                       const int*  __restrict__ countsg,
                                                       float* __restrict__ spill_all,
                                                       float* __restrict__ out)
{
    __shared__ float val[MAXS][BSLICE];       // 48 KB
    __shared__ int4  enc_s[ENC_CAP];          // 4 KB
    __shared__ unsigned char ops_s[ENC_CAP];
    __shared__ int counts_s[LEVELS];
    const int tid  = threadIdx.x;
    const int lane = tid & 63;
    const int wave = tid >> 6;                // 0..7
    const int b0   = blockIdx.x * BSLICE;
    float* spill = spill_all + (size_t)blockIdx.x * (CAP - MAXS) * BSLICE;

    for (int i = tid; i < ENC_CAP; i += ETHR) {
        enc_s[i] = enc4g[i];
        ops_s[i] = (unsigned char)opsg[i];
    }
    if (tid < LEVELS) counts_s[tid] = countsg[tid];
    __syncthreads();

    int sb = 0;
    for (int l = 0; l < LEVELS; ++l) {
        const int n = counts_s[l];
        for (int i0 = wave * CHUNK; i0 < n; i0 += 8 * CHUNK) {
            float v[CHUNK][4];
            int   om[CHUNK], cm[CHUNK], wr[CHUNK];
            // ---- gather: all 32 loads issued, no early exits ----
            #pragma unroll
            for (int j = 0; j < CHUNK; ++j) {
                const int i  = i0 + j;
                wr[j] = (i < n);
                const int slot = wr[j] ? (sb + i) : sb;   // dummy = slot sb (valid)
                const int4 e = (slot < ENC_CAP) ? enc_s[slot] : enc4g[slot];
                om[j] = (slot < ENC_CAP) ? ops_s[slot] : opsg[slot];
                const int es[4] = {e.x, e.y, e.z, e.w};
                int cmj = 0;
                #pragma unroll
                for (int k = 0; k < 4; ++k) {
                    const int s = es[k];      // wave-uniform
                    float t;
                    if (s < 0) {              // leaf code -> var row
                        const int cc = s + 2 * LEAVES;    // [0,4096)
                        t = xT[(size_t)(cc & (NUM_VARS - 1)) * BATCH + b0 + lane];
                        if (cc >= NUM_VARS) cmj |= (1 << k);
                    } else if (s < MAXS) {
                        t = val[s][lane];
                    } else {
                        t = spill[(size_t)(s - MAXS) * BSLICE + lane];
                    }
                    v[j][k] = t;
                }
                cm[j] = cmj;
            }
            // ---- combine + guarded stores ----
            #pragma unroll
            for (int j = 0; j < CHUNK; ++j) {
                const int i = i0 + j;
                const int slot = sb + i;
                float c0 = (cm[j] & 1) ? 1.0f - v[j][0] : v[j][0];
                float c1 = (cm[j] & 2) ? 1.0f - v[j][1] : v[j][1];
                float c2 = (cm[j] & 4) ? 1.0f - v[j][2] : v[j][2];
                float c3 = (cm[j] & 8) ? 1.0f - v[j][3] : v[j][3];
                const float r = (om[j] == 0)
                    ? ((c0 * c1) * c2) * c3               // np.prod order
                    : ((c0 + c1) + c2) + c3;              // np.sum order
                if (wr[j]) {
                    if (slot < MAXS) val[slot][lane] = r;
                    else spill[(size_t)(slot - MAXS) * BSLICE + lane] = r;
                    if (l == LEVELS - 1 && i == n - 1) out[b0 + lane] = r; // root
                }
            }
        }
        __syncthreads();
        sb += n;
    }
}

extern "C" void kernel_launch(void* const* d_in, const int* in_sizes, int n_in,
                              void* d_out, int out_size, void* d_ws, size_t ws_size,
                              hipStream_t stream)
{
    const float* x       = (const float*)d_in[0];
    const int4*  child4  = (const int4*)d_in[1];
    const int*   op_type = (const int*)d_in[2];
    float*       out     = (float*)d_out;

    char* w = (char*)d_ws;
    float* xT     = (float*)w;  w += (size_t)NUM_VARS * BATCH * sizeof(float); // 8 MB
    int4*  enc4   = (int4*)w;   w += (size_t)CAP * sizeof(int4);
    int*   ops    = (int*)w;    w += (size_t)CAP * sizeof(int);
    int*   counts = (int*)w;    w += 64;
    float* spill  = (float*)w;  // 16 * 1856 * 64 * 4 ≈ 7.6 MB

    {
        dim3 blk(64, 16);
        dim3 grd(NUM_VARS / 64, BATCH / 64);
        transpose_kernel<<<grd, blk, 0, stream>>>(x, xT);
    }
    mark_build_kernel<<<1, 1024, 0, stream>>>(child4, op_type, enc4, ops, counts);
    eval_kernel<<<NEVB, ETHR, 0, stream>>>(xT, enc4, ops, counts, spill, out);
}

// Round 12
// 96.831 us; speedup vs baseline: 2.4286x; 1.7062x over previous
//
#include <hip/hip_runtime.h>

#define BATCH    1024
#define NUM_VARS 2048
#define LEAVES   (2 * NUM_VARS)              // 4096
#define LEVELS   12
#define WIDTH    4096
#define TOTAL    (LEAVES + LEVELS * WIDTH)   // 53248
#define NWORDS   (TOTAL / 32)                // 1664 bitmask words

#define CAP      2048                        // max active nodes (validated S<=CAP r10/11)
#define BSLICE   64                          // batch elems per eval block
#define NEVB     (BATCH / BSLICE)            // 16 eval blocks
#define ETHR     512                         // 8 waves per eval block
#define CHUNK    4                           // nodes per wave per gather round

// Value buffer G: rows of 1024 floats. Rows [0,2048) = leaf vars (xT).
// Rows [2048, 2048+S) = active-node slots. Child code packing:
//   bits 0..13  : row index
//   bit 14      : complement (leaf 1-x)
//   bit 20      : op (only in e.x; 0=prod, 1=sum)

// ---------------------------------------------------------------------------
// Fused setup: blocks 0..511 transpose x into G rows [0,2048);
// block 512 does reachability + record build (independent of x).
// ---------------------------------------------------------------------------
__global__ __launch_bounds__(1024) void setup_kernel(const float* __restrict__ x,
                                                     const int4* __restrict__ child4,
                                                     const int*  __restrict__ op_type,
                                                     float* __restrict__ G,
                                                     int4* __restrict__ enc4,
                                                     int*  __restrict__ counts)
{
    const int tid = threadIdx.x;

    if (blockIdx.x < 512) {
        // ---- transpose tile: x[b][v] -> G[v][b] ----
        __shared__ float tile[64][65];
        const int v0 = (blockIdx.x & 31) * 64;
        const int bb = (blockIdx.x >> 5) * 64;
        const int tv = tid & 63;
        const int tb = tid >> 6;              // 0..15
        #pragma unroll
        for (int i = 0; i < 4; ++i) {
            const int bl = tb + i * 16;
            tile[tv][bl] = x[(size_t)(bb + bl) * NUM_VARS + v0 + tv];  // coalesced
        }
        __syncthreads();
        #pragma unroll
        for (int i = 0; i < 4; ++i) {
            const int vl = tb + i * 16;
            G[(size_t)(v0 + vl) * BATCH + bb + tv] = tile[vl][tv];     // coalesced
        }
        return;
    }

    // ---- block 512: reachability + record build ----
    __shared__ unsigned int flg[NWORDS];      // 6.5 KB bitmask
    __shared__ int nid[CAP];                  // sorted active node ids
    __shared__ int lvl_cnt[LEVELS], lvl_base[LEVELS];
    __shared__ int total_s;
    const int lane = tid & 63;
    const int wv   = tid >> 6;                // 0..15

    for (int i = tid; i < NWORDS; i += 1024) flg[i] = 0u;
    __syncthreads();
    if (tid == 0) flg[NWORDS - 1] = 0x80000000u;          // root = TOTAL-1
    __syncthreads();

    // backward marking: thread tests its 4 node bits, loads child4 under flag
    for (int l = LEVELS - 1; l >= 0; --l) {
        const int wbase = 128 * (l + 1);
        #pragma unroll
        for (int j = 0; j < 4; ++j) {
            const int k = (tid << 2) | j;     // node index within level
            if ((flg[wbase + (k >> 5)] >> (k & 31)) & 1u) {
                const int4 c = child4[l * WIDTH + k];
                atomicOr(&flg[c.x >> 5], 1u << (c.x & 31));
                atomicOr(&flg[c.y >> 5], 1u << (c.y & 31));
                atomicOr(&flg[c.z >> 5], 1u << (c.z & 31));
                atomicOr(&flg[c.w >> 5], 1u << (c.w & 31));
            }
        }
        __syncthreads();
    }

    // parallel per-level compaction counts (wave wv <-> level wv)
    if (wv < LEVELS) {
        const unsigned int w0 = flg[128 * (wv + 1) + 2 * lane];
        const unsigned int w1 = flg[128 * (wv + 1) + 2 * lane + 1];
        const int pc = __popc(w0) + __popc(w1);
        int scan = pc;
        for (int d = 1; d < 64; d <<= 1) {
            const int up = __shfl_up(scan, d, 64);
            if (lane >= d) scan += up;
        }
        if (lane == 63) lvl_cnt[wv] = scan;
    }
    __syncthreads();
    if (tid == 0) {
        int s = 0;
        for (int l = 0; l < LEVELS; ++l) { lvl_base[l] = s; s += lvl_cnt[l]; }
        total_s = (s < CAP) ? s : CAP;
        for (int l = 0; l < LEVELS; ++l) counts[l] = lvl_cnt[l];
        counts[LEVELS] = total_s;
    }
    __syncthreads();
    if (wv < LEVELS) {                        // write sorted ids
        const unsigned int w0 = flg[128 * (wv + 1) + 2 * lane];
        const unsigned int w1 = flg[128 * (wv + 1) + 2 * lane + 1];
        const int pc = __popc(w0) + __popc(w1);
        int scan = pc;
        for (int d = 1; d < 64; d <<= 1) {
            const int up = __shfl_up(scan, d, 64);
            if (lane >= d) scan += up;
        }
        int base = lvl_base[wv] + scan - pc;
        const int nd0 = LEAVES + wv * WIDTH + 64 * lane;
        unsigned int w = w0;
        while (w) { const int b = __ffs(w) - 1; w &= w - 1;
                    if (base < CAP) nid[base] = nd0 + b;      base++; }
        w = w1;
        while (w) { const int b = __ffs(w) - 1; w &= w - 1;
                    if (base < CAP) nid[base] = nd0 + 32 + b; base++; }
    }
    __syncthreads();

    // one-pass record build; 4-way interleaved branchless binary search
    const int S = total_s;
    for (int slot = tid; slot < S; slot += 1024) {
        const int nd = nid[slot];
        const int4 c = child4[nd - LEAVES];
        const int  o = op_type[nd - LEAVES];
        int lo0 = 0, lo1 = 0, lo2 = 0, lo3 = 0;
        int hi0 = S, hi1 = S, hi2 = S, hi3 = S;
        #pragma unroll
        for (int it = 0; it < 11; ++it) {     // 2^11 >= CAP
            const int m0 = (lo0 + hi0) >> 1, m1 = (lo1 + hi1) >> 1;
            const int m2 = (lo2 + hi2) >> 1, m3 = (lo3 + hi3) >> 1;
            const int n0 = nid[m0], n1 = nid[m1], n2 = nid[m2], n3 = nid[m3];
            if (lo0 < hi0) { if (n0 < c.x) lo0 = m0 + 1; else hi0 = m0; }
            if (lo1 < hi1) { if (n1 < c.y) lo1 = m1 + 1; else hi1 = m1; }
            if (lo2 < hi2) { if (n2 < c.z) lo2 = m2 + 1; else hi2 = m2; }
            if (lo3 < hi3) { if (n3 < c.w) lo3 = m3 + 1; else hi3 = m3; }
        }
        int4 e;
        e.x = (c.x < NUM_VARS) ? c.x : (c.x < LEAVES) ? ((c.x - NUM_VARS) | 0x4000)
                                                      : (NUM_VARS + lo0);
        e.y = (c.y < NUM_VARS) ? c.y : (c.y < LEAVES) ? ((c.y - NUM_VARS) | 0x4000)
                                                      : (NUM_VARS + lo1);
        e.z = (c.z < NUM_VARS) ? c.z : (c.z < LEAVES) ? ((c.z - NUM_VARS) | 0x4000)
                                                      : (NUM_VARS + lo2);
        e.w = (c.w < NUM_VARS) ? c.w : (c.w < LEAVES) ? ((c.w - NUM_VARS) | 0x4000)
                                                      : (NUM_VARS + lo3);
        e.x |= o << 20;
        enc4[slot] = e;
    }
}

// ---------------------------------------------------------------------------
// Evaluation: block b owns batch columns [b*64, b*64+64). Straight-line
// gather: every child value is G[row*1024 + boff] — NO branches around
// loads; complement and op resolved with selects. Block-local global
// writes to G become visible across __syncthreads (same CU).
// ---------------------------------------------------------------------------
__global__ __launch_bounds__(ETHR) void eval_kernel(float* __restrict__ G,
                                                    const int4* __restrict__ enc4g,
                                                    const int*  __restrict__ countsg,
                                                    float* __restrict__ out)
{
    __shared__ int4 enc_s[CAP];               // 32 KB
    __shared__ int counts_s[LEVELS + 1];
    const int tid  = threadIdx.x;
    const int lane = tid & 63;
    const int wave = tid >> 6;                // 0..7
    const int boff = blockIdx.x * BSLICE + lane;

    if (tid < LEVELS + 1) counts_s[tid] = countsg[tid];
    __syncthreads();
    const int S = counts_s[LEVELS];
    for (int i = tid; i < S; i += ETHR) enc_s[i] = enc4g[i];  // coalesced preload
    __syncthreads();

    int sb = 0;
    for (int l = 0; l < LEVELS; ++l) {
        const int n = counts_s[l];
        for (int i0 = wave * CHUNK; i0 < n; i0 += 8 * CHUNK) {
            int4  ec[CHUNK];
            int   wr[CHUNK];
            float v[CHUNK][4];
            // ---- gather: straight-line, all 16 loads independent ----
            #pragma unroll
            for (int j = 0; j < CHUNK; ++j) {
                const int i = i0 + j;
                wr[j] = (i < n);
                const int slot = sb + (wr[j] ? i : 0);    // clamp: row stays valid
                const int4 e = enc_s[slot];
                ec[j] = e;
                v[j][0] = G[(size_t)(e.x & 0x3FFF) * BATCH + boff];
                v[j][1] = G[(size_t)(e.y & 0x3FFF) * BATCH + boff];
                v[j][2] = G[(size_t)(e.z & 0x3FFF) * BATCH + boff];
                v[j][3] = G[(size_t)(e.w & 0x3FFF) * BATCH + boff];
            }
            // ---- combine: selects only, no branches ----
            #pragma unroll
            for (int j = 0; j < CHUNK; ++j) {
                const int4 e = ec[j];
                const float c0 = (e.x & 0x4000) ? 1.0f - v[j][0] : v[j][0];
                const float c1 = (e.y & 0x4000) ? 1.0f - v[j][1] : v[j][1];
                const float c2 = (e.z & 0x4000) ? 1.0f - v[j][2] : v[j][2];
                const float c3 = (e.w & 0x4000) ? 1.0f - v[j][3] : v[j][3];
                const float p = ((c0 * c1) * c2) * c3;    // np.prod order
                const float s = ((c0 + c1) + c2) + c3;    // np.sum order
                const float r = (e.x & (1 << 20)) ? s : p;
                if (wr[j]) {
                    const int i = i0 + j;
                    G[(size_t)(NUM_VARS + sb + i) * BATCH + boff] = r;
                    if (l == LEVELS - 1 && i == n - 1) out[boff] = r;   // root
                }
            }
        }
        __syncthreads();
        sb += n;
    }
}

extern "C" void kernel_launch(void* const* d_in, const int* in_sizes, int n_in,
                              void* d_out, int out_size, void* d_ws, size_t ws_size,
                              hipStream_t stream)
{
    const float* x       = (const float*)d_in[0];
    const int4*  child4  = (const int4*)d_in[1];
    const int*   op_type = (const int*)d_in[2];
    float*       out     = (float*)d_out;

    char* w = (char*)d_ws;
    float* G      = (float*)w;  w += (size_t)(NUM_VARS + CAP) * BATCH * sizeof(float); // 16 MB
    int4*  enc4   = (int4*)w;   w += (size_t)CAP * sizeof(int4);                       // 32 KB
    int*   counts = (int*)w;    w += 64;

    setup_kernel<<<513, 1024, 0, stream>>>(x, child4, op_type, G, enc4, counts);
    eval_kernel<<<NEVB, ETHR, 0, stream>>>(G, enc4, counts, out);
}